// Round 10
// baseline (130.894 us; speedup 1.0000x reference)
//
#include <hip/hip_runtime.h>
#include <math.h>

#define EPS 1e-5f
#define N0 1000
#define NK1 500
#define NK2 100
#define NE 32000
#define NBLK 64

__device__ __forceinline__ float bnr(float h, float sc, float sh) {
    float v = fmaf(h, sc, sh);
    return v > 0.f ? v : 0.f;
}

// All cross-block workspace traffic goes through RELAXED agent-scope atomics:
// these compile to global ops that bypass the non-coherent L1/L2 and hit the
// coherence point, so no buffer_wbl2/buffer_inv fences are ever required.
__device__ __forceinline__ float aload(const float* p) {
    return __hip_atomic_load(p, __ATOMIC_RELAXED, __HIP_MEMORY_SCOPE_AGENT);
}
__device__ __forceinline__ void astore(float* p, float v) {
    __hip_atomic_store(p, v, __ATOMIC_RELAXED, __HIP_MEMORY_SCOPE_AGENT);
}
__device__ __forceinline__ int aiload(const int* p) {
    return __hip_atomic_load(p, __ATOMIC_RELAXED, __HIP_MEMORY_SCOPE_AGENT);
}
__device__ __forceinline__ void aistore(int* p, int v) {
    __hip_atomic_store(p, v, __ATOMIC_RELAXED, __HIP_MEMORY_SCOPE_AGENT);
}

// Fence-free grid barrier. R9 change: poll period s_sleep(1)->s_sleep(64)
// (~1.7us). Hypothesis: dense polling from 64 blocks saturates the barrier
// cache line at the coherence point and serializes arrivals (=> the observed
// ~13us/sync). Sparse polling leaves the line idle so arrivals complete in
// ~ns and detection adds <=1 poll period.
__device__ __forceinline__ void gsync(unsigned* bar, unsigned k) {
    asm volatile("s_waitcnt vmcnt(0) lgkmcnt(0)" ::: "memory");
    __syncthreads();
    if (threadIdx.x == 0) {
        __hip_atomic_fetch_add(bar, 1u, __ATOMIC_RELAXED, __HIP_MEMORY_SCOPE_AGENT);
        const unsigned target = NBLK * k;
        unsigned spins = 0;
        // first check happens BEFORE any sleep: late arrivals pass instantly
        while (__hip_atomic_load(bar, __ATOMIC_RELAXED, __HIP_MEMORY_SCOPE_AGENT) < target) {
            if (++spins > (1u << 14)) break;  // hang safety (~28 ms)
            __builtin_amdgcn_s_sleep(64);     // ~4096 cycles between polls
        }
    }
    __syncthreads();
}

struct Args {
    const float *x; const int *ei; const float *ea;
    const float *w0, *b0, *g0, *be0;
    const float *w1, *b1, *g1, *be1;
    const float *w2a, *b2a, *g2a, *be2a;
    const float *w2b, *b2b, *g2b, *be2b;
    const float *w3a, *b3a, *w3b, *b3b;
    const float *p1_wrel, *p1_wroot, *p1_b, *p2_wrel, *p2_wroot, *p2_b;
    float *h1, *psum1, *sc1, *t1, *xp1, *h2a, *psum2a;
    float *h2b, *psum2b, *t2, *sc2, *xp2;
    int *rk_g, *nsrc, *ndst; float *new_ew;
    unsigned *bar;
    float *out;
};

__global__ __launch_bounds__(256) void k_mega(Args a) {
    union __align__(16) SMem {
        struct { float xs[32][68], wsm[64][65], rs[256], rq[256], sc0[64], sh0[64]; } m1;
        struct { float xs[16][68], wsm[128][65], rs[256], rq[256]; } m2;
        struct { float wsm[200][33], xs[8][36], sc[128], sh[128]; } m3;
        struct { float acc[N0]; } sct;
        struct { float ss[N0], sc[200], sh[200]; } rk;
        struct { float sc[200], sh[200]; } bn;
        struct { float g[200], h3[128], o[2]; } fin;
    };
    __shared__ SMem sm;
    const int b = blockIdx.x, t = threadIdx.x;
    const int lane = t & 63, wv = t >> 6;

    // ======== P1: lin0+lin1 fused (32 blocks x 32-node tiles) ========
    if (b < 32) {
        const int c = lane, slot = wv;
        const int nb = b * 32;
        {
            float wa = a.w0[c * 3], wb = a.w0[c * 3 + 1], wc = a.w0[c * 3 + 2], bb = a.b0[c];
            float s = 0.f, q = 0.f;
            for (int n = slot; n < N0; n += 4) {
                float h = fmaf(wa, a.x[n * 3], fmaf(wb, a.x[n * 3 + 1], fmaf(wc, a.x[n * 3 + 2], bb)));
                s += h; q += h * h;
            }
            sm.m1.rs[t] = s; sm.m1.rq[t] = q;
            __syncthreads();
            if (t < 64) {
                float S = sm.m1.rs[t] + sm.m1.rs[t + 64] + sm.m1.rs[t + 128] + sm.m1.rs[t + 192];
                float Q = sm.m1.rq[t] + sm.m1.rq[t + 64] + sm.m1.rq[t + 128] + sm.m1.rq[t + 192];
                float mu = S * (1.f / N0);
                float var = Q * (1.f / N0) - mu * mu;
                float sv = a.g0[t] * rsqrtf(var + EPS);
                sm.m1.sc0[t] = sv; sm.m1.sh0[t] = a.be0[t] - mu * sv;
            }
            __syncthreads();
        }
        for (int i = 0; i < 8; ++i) {
            int e = t + i * 256;
            int r = e >> 6, cc = e & 63;
            int n = nb + r;
            float v = 0.f;
            if (n < N0) {
                float h = fmaf(a.w0[cc * 3], a.x[n * 3],
                          fmaf(a.w0[cc * 3 + 1], a.x[n * 3 + 1],
                          fmaf(a.w0[cc * 3 + 2], a.x[n * 3 + 2], a.b0[cc])));
                v = bnr(h, sm.m1.sc0[cc], sm.m1.sh0[cc]);
            }
            sm.m1.xs[r][cc] = v;
        }
        for (int i = 0; i < 16; ++i) {
            int e = t + i * 256;
            sm.m1.wsm[e >> 6][e & 63] = a.w1[e];
        }
        __syncthreads();
        float sacc = 0.f, qacc = 0.f;
        float bb1 = a.b1[c];
        for (int g = 0; g < 2; ++g) {
            int r0 = slot * 8 + g * 4;
            float a0 = bb1, a1 = bb1, a2 = bb1, a3 = bb1;
            #pragma unroll
            for (int kq = 0; kq < 16; ++kq) {
                float w0v = sm.m1.wsm[c][4 * kq], w1v = sm.m1.wsm[c][4 * kq + 1];
                float w2v = sm.m1.wsm[c][4 * kq + 2], w3v = sm.m1.wsm[c][4 * kq + 3];
                float4 x0 = *(const float4*)&sm.m1.xs[r0 + 0][4 * kq];
                float4 x1 = *(const float4*)&sm.m1.xs[r0 + 1][4 * kq];
                float4 x2 = *(const float4*)&sm.m1.xs[r0 + 2][4 * kq];
                float4 x3 = *(const float4*)&sm.m1.xs[r0 + 3][4 * kq];
                a0 = fmaf(x0.x, w0v, fmaf(x0.y, w1v, fmaf(x0.z, w2v, fmaf(x0.w, w3v, a0))));
                a1 = fmaf(x1.x, w0v, fmaf(x1.y, w1v, fmaf(x1.z, w2v, fmaf(x1.w, w3v, a1))));
                a2 = fmaf(x2.x, w0v, fmaf(x2.y, w1v, fmaf(x2.z, w2v, fmaf(x2.w, w3v, a2))));
                a3 = fmaf(x3.x, w0v, fmaf(x3.y, w1v, fmaf(x3.z, w2v, fmaf(x3.w, w3v, a3))));
            }
            float av[4] = {a0, a1, a2, a3};
            #pragma unroll
            for (int i = 0; i < 4; ++i) {
                int n = nb + r0 + i;
                if (n < N0) {
                    astore(&a.h1[n * 64 + c], av[i]);
                    sacc += av[i]; qacc += av[i] * av[i];
                }
            }
        }
        sm.m1.rs[t] = sacc; sm.m1.rq[t] = qacc;
        __syncthreads();
        if (t < 64) {
            astore(&a.psum1[b * 128 + t],      sm.m1.rs[t] + sm.m1.rs[t + 64] + sm.m1.rs[t + 128] + sm.m1.rs[t + 192]);
            astore(&a.psum1[b * 128 + 64 + t], sm.m1.rq[t] + sm.m1.rq[t + 64] + sm.m1.rq[t + 128] + sm.m1.rq[t + 192]);
        }
    }
    gsync(a.bar, 1);

    // ======== P2: score1 (63 blocks x 16 nodes, wave-per-node) ========
    if (b < 63) {
        if (t < 64) {
            float s = 0.f, q = 0.f;
            for (int i = 0; i < 32; ++i) { s += aload(&a.psum1[i * 128 + t]); q += aload(&a.psum1[i * 128 + 64 + t]); }
            float mu = s * (1.f / N0);
            float var = q * (1.f / N0) - mu * mu;
            float sv = a.g1[t] * rsqrtf(var + EPS);
            sm.bn.sc[t] = sv; sm.bn.sh[t] = a.be1[t] - mu * sv;
        }
        __syncthreads();
        for (int it = 0; it < 4; ++it) {
            int n = b * 16 + it * 4 + wv;
            if (n < N0) {
                float v = bnr(aload(&a.h1[n * 64 + lane]), sm.bn.sc[lane], sm.bn.sh[lane]);
                float dr = v * a.p1_wrel[lane], dt = v * a.p1_wroot[lane];
                #pragma unroll
                for (int m = 32; m >= 1; m >>= 1) {
                    dr += __shfl_xor(dr, m, 64);
                    dt += __shfl_xor(dt, m, 64);
                }
                if (lane == 0) { astore(&a.t1[n], dr); astore(&a.sc1[n], dt + a.p1_b[0]); }
            }
        }
    }
    gsync(a.bar, 2);

    // ======== P3: scatter1 (16 blocks, LDS-aggregated) ========
    if (b < 16) {
        for (int i = t; i < N0; i += 256) sm.sct.acc[i] = 0.f;
        __syncthreads();
        for (int e = b * 256 + t; e < NE; e += 16 * 256) {
            float w = a.ea[e];
            if (w != 0.f) atomicAdd(&sm.sct.acc[a.ei[NE + e]], w * aload(&a.t1[a.ei[e]]));
        }
        __syncthreads();
        for (int i = t; i < N0; i += 256) {
            float v = sm.sct.acc[i];
            if (v != 0.f) atomicAdd(&a.sc1[i], v);
        }
    }
    gsync(a.bar, 3);

    // ======== P4: rank1 + select (63 blocks x 16 nodes) ========
    if (b < 63) {
        if (t < 64) {
            float s = 0.f, q = 0.f;
            for (int i = 0; i < 32; ++i) { s += aload(&a.psum1[i * 128 + t]); q += aload(&a.psum1[i * 128 + 64 + t]); }
            float mu = s * (1.f / N0);
            float var = q * (1.f / N0) - mu * mu;
            float sv = a.g1[t] * rsqrtf(var + EPS);
            sm.rk.sc[t] = sv; sm.rk.sh[t] = a.be1[t] - mu * sv;
        }
        for (int i = t; i < N0; i += 256) sm.rk.ss[i] = aload(&a.sc1[i]);
        __syncthreads();
        for (int it = 0; it < 4; ++it) {
            int n = b * 16 + it * 4 + wv;
            if (n < N0) {
                float s = sm.rk.ss[n];
                int r = 0;
                for (int m = lane; m < N0; m += 64) {
                    float smv = sm.rk.ss[m];
                    r += (smv > s) || (smv == s && m < n);
                }
                #pragma unroll
                for (int msk = 32; msk >= 1; msk >>= 1) r += __shfl_xor(r, msk, 64);
                if (lane == 0) aistore(&a.rk_g[n], r);
                if (r < NK1) {
                    float tn = tanhf(s);
                    astore(&a.xp1[r * 64 + lane],
                           bnr(aload(&a.h1[n * 64 + lane]), sm.rk.sc[lane], sm.rk.sh[lane]) * tn);
                }
            }
        }
    }
    gsync(a.bar, 4);

    // ======== P5: lin2a (32 blocks x 16 rows) + remap (32 blocks) ========
    if (b < 32) {
        const int nb = b * 16;
        const int nrows = (NK1 - nb) < 16 ? (NK1 - nb) : 16;
        for (int i = 0; i < 4; ++i) {
            int e = t + i * 256;
            int r = e >> 6, cc = e & 63;
            sm.m2.xs[r][cc] = (r < nrows) ? aload(&a.xp1[(nb + r) * 64 + cc]) : 0.f;
        }
        for (int i = 0; i < 32; ++i) {
            int e = t + i * 256;
            sm.m2.wsm[e >> 6][e & 63] = a.w2a[e];
        }
        __syncthreads();
        const int c = t & 127, slot = t >> 7;
        float sacc = 0.f, qacc = 0.f;
        float bb2 = a.b2a[c];
        for (int g = 0; g < 2; ++g) {
            int r0 = slot * 8 + g * 4;
            float a0 = bb2, a1 = bb2, a2 = bb2, a3 = bb2;
            #pragma unroll
            for (int kq = 0; kq < 16; ++kq) {
                float w0v = sm.m2.wsm[c][4 * kq], w1v = sm.m2.wsm[c][4 * kq + 1];
                float w2v = sm.m2.wsm[c][4 * kq + 2], w3v = sm.m2.wsm[c][4 * kq + 3];
                float4 x0 = *(const float4*)&sm.m2.xs[r0 + 0][4 * kq];
                float4 x1 = *(const float4*)&sm.m2.xs[r0 + 1][4 * kq];
                float4 x2 = *(const float4*)&sm.m2.xs[r0 + 2][4 * kq];
                float4 x3 = *(const float4*)&sm.m2.xs[r0 + 3][4 * kq];
                a0 = fmaf(x0.x, w0v, fmaf(x0.y, w1v, fmaf(x0.z, w2v, fmaf(x0.w, w3v, a0))));
                a1 = fmaf(x1.x, w0v, fmaf(x1.y, w1v, fmaf(x1.z, w2v, fmaf(x1.w, w3v, a1))));
                a2 = fmaf(x2.x, w0v, fmaf(x2.y, w1v, fmaf(x2.z, w2v, fmaf(x2.w, w3v, a2))));
                a3 = fmaf(x3.x, w0v, fmaf(x3.y, w1v, fmaf(x3.z, w2v, fmaf(x3.w, w3v, a3))));
            }
            float av[4] = {a0, a1, a2, a3};
            #pragma unroll
            for (int i = 0; i < 4; ++i) {
                int r = r0 + i;
                if (r < nrows) {
                    astore(&a.h2a[(nb + r) * 128 + c], av[i]);
                    sacc += av[i]; qacc += av[i] * av[i];
                }
            }
        }
        sm.m2.rs[t] = sacc; sm.m2.rq[t] = qacc;
        __syncthreads();
        if (t < 128) {
            astore(&a.psum2a[b * 256 + t],       sm.m2.rs[t] + sm.m2.rs[t + 128]);
            astore(&a.psum2a[b * 256 + 128 + t], sm.m2.rq[t] + sm.m2.rq[t + 128]);
        }
    } else {
        for (int e = (b - 32) * 1000 + t; e < (b - 32) * 1000 + 1000; e += 256) {
            int s_ = a.ei[e], d_ = a.ei[NE + e];
            int rs_ = aiload(&a.rk_g[s_]), rd_ = aiload(&a.rk_g[d_]);
            bool v = (rs_ < NK1) && (rd_ < NK1);
            aistore(&a.nsrc[e], v ? rs_ : 0);
            aistore(&a.ndst[e], v ? rd_ : 0);
            astore(&a.new_ew[e], v ? a.ea[e] : 0.f);
        }
    }
    gsync(a.bar, 5);

    // ======== P6: lin2b (64 blocks x 8 rows, k-tiled) ========
    {
        const int nb = b * 8;
        if (nb < NK1) {
            const int nrows = (NK1 - nb) < 8 ? (NK1 - nb) : 8;
            if (t < 128) {
                float s = 0.f, q = 0.f;
                for (int i = 0; i < 32; ++i) { s += aload(&a.psum2a[i * 256 + t]); q += aload(&a.psum2a[i * 256 + 128 + t]); }
                float mu = s * (1.f / NK1);
                float var = q * (1.f / NK1) - mu * mu;
                float sv = a.g2a[t] * rsqrtf(var + EPS);
                sm.m3.sc[t] = sv; sm.m3.sh[t] = a.be2a[t] - mu * sv;
            }
            float acc[8];
            float bb = (t < 200) ? a.b2b[t] : 0.f;
            #pragma unroll
            for (int r = 0; r < 8; ++r) acc[r] = bb;
            for (int kt = 0; kt < 4; ++kt) {
                int k0 = kt * 32;
                __syncthreads();
                for (int i = 0; i < 25; ++i) {
                    int e = t + i * 256;
                    int r = e >> 5, k = e & 31;
                    sm.m3.wsm[r][k] = a.w2b[r * 128 + k0 + k];
                }
                {
                    int r = t >> 5, k = t & 31;
                    sm.m3.xs[r][k] = (r < nrows)
                        ? bnr(aload(&a.h2a[(nb + r) * 128 + k0 + k]), sm.m3.sc[k0 + k], sm.m3.sh[k0 + k])
                        : 0.f;
                }
                __syncthreads();
                if (t < 200) {
                    #pragma unroll
                    for (int kq = 0; kq < 8; ++kq) {
                        float w0v = sm.m3.wsm[t][4 * kq],     w1v = sm.m3.wsm[t][4 * kq + 1];
                        float w2v = sm.m3.wsm[t][4 * kq + 2], w3v = sm.m3.wsm[t][4 * kq + 3];
                        #pragma unroll
                        for (int r = 0; r < 8; ++r) {
                            float4 xv = *(const float4*)&sm.m3.xs[r][4 * kq];
                            acc[r] = fmaf(xv.x, w0v, fmaf(xv.y, w1v, fmaf(xv.z, w2v, fmaf(xv.w, w3v, acc[r]))));
                        }
                    }
                }
            }
            if (t < 200) {
                float s = 0.f, q = 0.f;
                #pragma unroll
                for (int r = 0; r < 8; ++r) {
                    if (r < nrows) {
                        astore(&a.h2b[(nb + r) * 200 + t], acc[r]);
                        s += acc[r]; q += acc[r] * acc[r];
                    }
                }
                astore(&a.psum2b[b * 400 + t], s);
                astore(&a.psum2b[b * 400 + 200 + t], q);
            }
        } else if (t < 200) {
            astore(&a.psum2b[b * 400 + t], 0.f);
            astore(&a.psum2b[b * 400 + 200 + t], 0.f);
        }
    }
    gsync(a.bar, 6);

    // ======== P7: score2 (63 blocks x 8 nodes) ========
    if (b < 63) {
        if (t < 200) {
            float s = 0.f, q = 0.f;
            for (int i = 0; i < 64; ++i) { s += aload(&a.psum2b[i * 400 + t]); q += aload(&a.psum2b[i * 400 + 200 + t]); }
            float mu = s * (1.f / NK1);
            float var = q * (1.f / NK1) - mu * mu;
            float sv = a.g2b[t] * rsqrtf(var + EPS);
            sm.bn.sc[t] = sv; sm.bn.sh[t] = a.be2b[t] - mu * sv;
        }
        __syncthreads();
        for (int it = 0; it < 2; ++it) {
            int n = b * 8 + it * 4 + wv;
            if (n < NK1) {
                float dr = 0.f, dt = 0.f;
                #pragma unroll
                for (int j = 0; j < 4; ++j) {
                    int ch = lane + 64 * j;
                    if (ch < 200) {
                        float v = bnr(aload(&a.h2b[n * 200 + ch]), sm.bn.sc[ch], sm.bn.sh[ch]);
                        dr = fmaf(v, a.p2_wrel[ch], dr);
                        dt = fmaf(v, a.p2_wroot[ch], dt);
                    }
                }
                #pragma unroll
                for (int m = 32; m >= 1; m >>= 1) {
                    dr += __shfl_xor(dr, m, 64);
                    dt += __shfl_xor(dt, m, 64);
                }
                if (lane == 0) { astore(&a.t2[n], dr); astore(&a.sc2[n], dt + a.p2_b[0]); }
            }
        }
    }
    gsync(a.bar, 7);

    // ======== P8: scatter2 (16 blocks) ========
    if (b < 16) {
        for (int i = t; i < NK1; i += 256) sm.sct.acc[i] = 0.f;
        __syncthreads();
        for (int e = b * 256 + t; e < NE; e += 16 * 256) {
            float w = aload(&a.new_ew[e]);
            if (w != 0.f) atomicAdd(&sm.sct.acc[aiload(&a.ndst[e])], w * aload(&a.t2[aiload(&a.nsrc[e])]));
        }
        __syncthreads();
        for (int i = t; i < NK1; i += 256) {
            float v = sm.sct.acc[i];
            if (v != 0.f) atomicAdd(&a.sc2[i], v);
        }
    }
    gsync(a.bar, 8);

    // ======== P9: rank2 + select (63 blocks x 8 nodes) ========
    if (b < 63) {
        if (t < 200) {
            float s = 0.f, q = 0.f;
            for (int i = 0; i < 64; ++i) { s += aload(&a.psum2b[i * 400 + t]); q += aload(&a.psum2b[i * 400 + 200 + t]); }
            float mu = s * (1.f / NK1);
            float var = q * (1.f / NK1) - mu * mu;
            float sv = a.g2b[t] * rsqrtf(var + EPS);
            sm.rk.sc[t] = sv; sm.rk.sh[t] = a.be2b[t] - mu * sv;
        }
        for (int i = t; i < NK1; i += 256) sm.rk.ss[i] = aload(&a.sc2[i]);
        __syncthreads();
        for (int it = 0; it < 2; ++it) {
            int n = b * 8 + it * 4 + wv;
            if (n < NK1) {
                float s = sm.rk.ss[n];
                int r = 0;
                for (int m = lane; m < NK1; m += 64) {
                    float smv = sm.rk.ss[m];
                    r += (smv > s) || (smv == s && m < n);
                }
                #pragma unroll
                for (int msk = 32; msk >= 1; msk >>= 1) r += __shfl_xor(r, msk, 64);
                if (r < NK2) {
                    float tn = tanhf(s);
                    #pragma unroll
                    for (int j = 0; j < 4; ++j) {
                        int ch = lane + 64 * j;
                        if (ch < 200)
                            astore(&a.xp2[r * 200 + ch],
                                   bnr(aload(&a.h2b[n * 200 + ch]), sm.rk.sc[ch], sm.rk.sh[ch]) * tn);
                    }
                }
            }
        }
    }
    gsync(a.bar, 9);

    // ======== P10: max-pool + mlp_third + log_softmax (block 0) ========
    if (b == 0) {
        if (t < 200) {
            float m = -1e30f;
            for (int n = 0; n < NK2; ++n) m = fmaxf(m, aload(&a.xp2[n * 200 + t]));
            sm.fin.g[t] = m;
        }
        __syncthreads();
        for (int r = wv; r < 128; r += 4) {
            float p = 0.f;
            #pragma unroll
            for (int j = 0; j < 4; ++j) {
                int ch = lane + 64 * j;
                if (ch < 200) p = fmaf(a.w3a[r * 200 + ch], sm.fin.g[ch], p);
            }
            #pragma unroll
            for (int m = 32; m >= 1; m >>= 1) p += __shfl_xor(p, m, 64);
            if (lane == 0) sm.fin.h3[r] = fmaxf(p + a.b3a[r], 0.f);
        }
        __syncthreads();
        if (t < 128) {
            int ow = t >> 6;
            float p = a.w3b[ow * 128 + lane] * sm.fin.h3[lane]
                    + a.w3b[ow * 128 + 64 + lane] * sm.fin.h3[64 + lane];
            #pragma unroll
            for (int m = 32; m >= 1; m >>= 1) p += __shfl_xor(p, m, 64);
            if (lane == 0) sm.fin.o[ow] = fmaxf(p + a.b3b[ow], 0.f);
        }
        __syncthreads();
        if (t == 0) {
            float m = fmaxf(sm.fin.o[0], sm.fin.o[1]);
            float l = m + logf(expf(sm.fin.o[0] - m) + expf(sm.fin.o[1] - m));
            a.out[0] = sm.fin.o[0] - l;
            a.out[1] = sm.fin.o[1] - l;
        }
    }
}

extern "C" void kernel_launch(void* const* d_in, const int* in_sizes, int n_in,
                              void* d_out, int out_size, void* d_ws, size_t ws_size,
                              hipStream_t stream) {
    float* ws = (float*)d_ws;

    Args a;
    a.x    = (const float*)d_in[0];
    a.ei   = (const int*)d_in[1];
    a.ea   = (const float*)d_in[2];
    a.w0   = (const float*)d_in[3];  a.b0   = (const float*)d_in[4];
    a.g0   = (const float*)d_in[5];  a.be0  = (const float*)d_in[6];
    a.w1   = (const float*)d_in[7];  a.b1   = (const float*)d_in[8];
    a.g1   = (const float*)d_in[9];  a.be1  = (const float*)d_in[10];
    a.w2a  = (const float*)d_in[11]; a.b2a  = (const float*)d_in[12];
    a.g2a  = (const float*)d_in[13]; a.be2a = (const float*)d_in[14];
    a.w2b  = (const float*)d_in[15]; a.b2b  = (const float*)d_in[16];
    a.g2b  = (const float*)d_in[17]; a.be2b = (const float*)d_in[18];
    a.w3a  = (const float*)d_in[19]; a.b3a  = (const float*)d_in[20];
    a.w3b  = (const float*)d_in[21]; a.b3b  = (const float*)d_in[22];
    a.p1_wrel  = (const float*)d_in[23];
    a.p1_wroot = (const float*)d_in[24];
    a.p1_b     = (const float*)d_in[25];
    a.p2_wrel  = (const float*)d_in[26];
    a.p2_wroot = (const float*)d_in[27];
    a.p2_b     = (const float*)d_in[28];

    a.h1     = ws;                      // 64000
    a.psum1  = ws + 64000;              // 4096  (32 x 128)
    a.rk_g   = (int*)(ws + 68096);      // 1000
    a.sc1    = ws + 69096;              // 1000
    a.t1     = ws + 70096;              // 1000
    a.xp1    = ws + 71096;              // 32000
    a.h2a    = ws + 103096;             // 64000
    a.psum2a = ws + 167096;             // 8192  (32 x 256)
    a.h2b    = ws + 175288;             // 100000
    a.psum2b = ws + 275288;             // 25600 (64 x 400)
    a.t2     = ws + 300888;             // 500
    a.sc2    = ws + 301388;             // 500
    a.xp2    = ws + 301888;             // 20000
    a.nsrc   = (int*)(ws + 321888);     // 32000
    a.ndst   = (int*)(ws + 353888);     // 32000
    a.new_ew = ws + 385888;             // 32000
    a.bar    = (unsigned*)(ws + 417888);
    a.out    = (float*)d_out;

    hipMemsetAsync((void*)a.bar, 0, sizeof(unsigned), stream);
    k_mega<<<NBLK, 256, 0, stream>>>(a);
}